// Round 18
// baseline (391.725 us; speedup 1.0000x reference)
//
#include <hip/hip_runtime.h>

// ---------------------------------------------------------------------------
// SlidingWindowGroupedAttention  (B=2, L=8192, E=1024, H=16, D=64, W=512, G=64)
// prep_all(ONE launch) -> merged Q+K+V projection GEMM (ONE launch; RoPE
// epilogue for Q/K halves, key-permuted vT epilogue for V tail blocks) ->
// grouped attention (R14, ~107us accepted) -> GEMM (+bias, fp32).
// 4 launches total. GEMM K-loop: BK=64, 128B LDS rows, XOR-8 swizzle.
// ---------------------------------------------------------------------------

typedef unsigned short ushort_t;
typedef __attribute__((ext_vector_type(8))) __bf16 bf16x8;
typedef __attribute__((ext_vector_type(4))) float f32x4;
typedef __attribute__((ext_vector_type(8))) unsigned short ushort8;
typedef __attribute__((ext_vector_type(4))) unsigned int u32x4;

#define MFMA16(a, b, c) __builtin_amdgcn_mfma_f32_16x16x32_bf16((a), (b), (c), 0, 0, 0)

static __device__ __forceinline__ ushort_t f2bf(float f) {
    unsigned u = __float_as_uint(f);
    u += 0x7fffu + ((u >> 16) & 1u);   // round-to-nearest-even
    return (ushort_t)(u >> 16);
}

// compiler-fusable bf16 convert (pairs become v_cvt_pk_bf16_f32; RTNE)
static __device__ __forceinline__ ushort_t f2bfc(float f) {
    __bf16 h = (__bf16)f;
    return __builtin_bit_cast(ushort_t, h);
}

typedef __attribute__((address_space(3))) unsigned int lds_u32;
typedef const __attribute__((address_space(1))) unsigned int glb_u32;

static __device__ __forceinline__ void gload_lds16(const void* g, void* l) {
    __builtin_amdgcn_global_load_lds((glb_u32*)g, (lds_u32*)l, 16, 0, 0);
}

static __device__ __forceinline__ void cvt8(const float* __restrict__ in,
                                            ushort_t* __restrict__ out, long i) {
    const float4* p = (const float4*)in + i * 2;
    float4 a = p[0], b = p[1];
    ushort8 o;
    o[0] = f2bf(a.x); o[1] = f2bf(a.y); o[2] = f2bf(a.z); o[3] = f2bf(a.w);
    o[4] = f2bf(b.x); o[5] = f2bf(b.y); o[6] = f2bf(b.z); o[7] = f2bf(b.w);
    *(ushort8*)(out + i * 8) = o;
}

// ---------------------------------------------------------------------------
// prep_all: ONE launch for all elementwise work (19968 blocks):
//   [0,8192)      query fp32->bf16            -> Xbf
//   [8192,16384)  key   fp32->bf16            -> keybf (= d_out scratch)
//   [16384,17408) rope sin/cos table
//   [17408,19456) weight cvt x4
//   [19456,19968) value rows l<512 compact+cvt -> vin
// ---------------------------------------------------------------------------
__global__ __launch_bounds__(256) void prep_all(const float* __restrict__ query,
                                                const float* __restrict__ key_,
                                                const float* __restrict__ w0,
                                                const float* __restrict__ w1,
                                                const float* __restrict__ w2,
                                                const float* __restrict__ w3,
                                                ushort_t* __restrict__ o0,
                                                ushort_t* __restrict__ o1,
                                                ushort_t* __restrict__ o2,
                                                ushort_t* __restrict__ o3,
                                                const float* __restrict__ value,
                                                ushort_t* __restrict__ vin,
                                                float2* __restrict__ rope,
                                                ushort_t* __restrict__ Xbf,
                                                ushort_t* __restrict__ keybf) {
    const int bid = blockIdx.x;
    if (bid < 8192) {
        cvt8(query, Xbf, (long)bid * 256 + threadIdx.x);
    } else if (bid < 16384) {
        cvt8(key_, keybf, (long)(bid - 8192) * 256 + threadIdx.x);
    } else if (bid < 17408) {
        int i = (bid - 16384) * 256 + threadIdx.x;  // 8192*32
        int l = i >> 5, j = i & 31;
        float inv = exp2f(-(float)j * 0.4152410118609203f);  // log2(10000)/32
        float a = (float)l * inv;
        rope[i] = make_float2(sinf(a), cosf(a));
    } else if (bid < 19456) {
        int b2 = bid - 17408;
        int wsel = b2 >> 9;
        const float* in = (wsel == 0) ? w0 : (wsel == 1) ? w1 : (wsel == 2) ? w2 : w3;
        ushort_t* out = (wsel == 0) ? o0 : (wsel == 1) ? o1 : (wsel == 2) ? o2 : o3;
        cvt8(in, out, (long)(b2 & 511) * 256 + threadIdx.x);
    } else {
        int i = (bid - 19456) * 256 + threadIdx.x;  // value rows l<512 compact
        int f = i * 8;
        int m = f >> 10, c = f & 1023;
        long src = ((long)(m >> 9) * 8192 + (m & 511)) * 1024 + c;
        const float4* p = (const float4*)(value + src);
        float4 a = p[0], b = p[1];
        ushort8 o;
        o[0] = f2bf(a.x); o[1] = f2bf(a.y); o[2] = f2bf(a.z); o[3] = f2bf(a.w);
        o[4] = f2bf(b.x); o[5] = f2bf(b.y); o[6] = f2bf(b.z); o[7] = f2bf(b.w);
        *(ushort8*)(vin + f) = o;
    }
}

// ---------------------------------------------------------------------------
// bf16 GEMM  C[M,1024] = A[M,1024] @ W[1024,1024]^T (+bias)
// 128x128 tile, BK=64, 4 waves (2x2), global_load_lds w16.
// LDS rows are 128B (full bank span); slot s of row r holds global chunk
// s ^ (r&7) -> ds_read_b128 spreads every quarter-wave across all 32 banks.
// MODE 1: MERGED Q+K+V projection, grid 264x8 = 2112 blocks:
//   raw < 1024:  query half (XCD swizzle), RoPE epilogue -> qrb
//   raw < 2048:  key half   (XCD swizzle), RoPE epilogue -> krb
//   raw >= 2048: V-projection blocks (64), key-permuted vT epilogue -> vTb
// MODE 2: fp32 out, XCD swizzle (grid 128x8).
// ---------------------------------------------------------------------------
template <int MODE>
__global__ __launch_bounds__(256) void gemm_bt(const ushort_t* __restrict__ A,
                                               const ushort_t* __restrict__ Bw,
                                               const float* __restrict__ bias,
                                               void* __restrict__ outp,
                                               const float2* __restrict__ rope,
                                               float oscale,
                                               const ushort_t* __restrict__ A2,
                                               const ushort_t* __restrict__ Bw2,
                                               const float* __restrict__ bias2,
                                               void* __restrict__ outp2,
                                               const ushort_t* __restrict__ A3,
                                               const ushort_t* __restrict__ Bw3,
                                               const float* __restrict__ bias3,
                                               void* __restrict__ outp3) {
    __shared__ __align__(16) ushort_t sA[128 * 64];   // 16KB, 128B rows
    __shared__ __align__(16) ushort_t sB[128 * 64];   // 16KB
    const int tid = threadIdx.x, lane = tid & 63, wv = tid >> 6;
    const int wr = wv >> 1, wc = wv & 1;

    int bmx, bny;
    bool isv = false;
    const ushort_t* Ause = A;
    const ushort_t* Wuse = Bw;
    const float* buse = bias;
    void* ouse = outp;
    if constexpr (MODE == 1) {
        int raw = blockIdx.x + 264 * (int)blockIdx.y;   // 0..2111
        if (raw < 2048) {
            int half = raw >> 10, q = raw & 1023;
            bmx = (q & 7) * 16 + ((q >> 3) & 15);
            bny = q >> 7;
            if (half) { Ause = A2; Wuse = Bw2; buse = bias2; ouse = outp2; }
        } else {
            int vid = raw - 2048;                        // 0..63
            bmx = vid & 7;
            bny = vid >> 3;
            isv = true;
            Ause = A3; Wuse = Bw3; buse = bias3; ouse = outp3;
        }
    } else {
        int id = blockIdx.x + 128 * (int)blockIdx.y;     // 0..1023
        bmx = (id & 7) * 16 + ((id >> 3) & 15);
        bny = id >> 7;
    }
    const long bm = (long)bmx * 128;
    const int bn = bny * 128;

    f32x4 acc[4][4] = {};

    // staging: per instruction 256 thr x 16B = 32 rows x 128B; 4 instr per
    // matrix per kt. thread -> (row32 = tid>>3, slot = tid&7); source chunk
    // ca = slot ^ (row & 7) (row&7 == row32&7 since i*32 = 0 mod 8).
    const int row32 = tid >> 3;      // 0..31
    const int sl8 = tid & 7;         // 16B slot 0..7
    const int ca = sl8 ^ (row32 & 7);
    const ushort_t* Ab = Ause + (bm + row32) * 1024 + ca * 8;
    const ushort_t* Bb = Wuse + (long)(bn + row32) * 1024 + ca * 8;
    ushort_t* la = &sA[tid * 8];     // row32*64 + sl8*8 == tid*8 (linear)
    ushort_t* lb = &sB[tid * 8];

    for (int kt = 0; kt < 16; ++kt) {
        const int ko = kt * 64;
#pragma unroll
        for (int i = 0; i < 4; ++i)
            gload_lds16(Ab + i * 32 * 1024 + ko, la + i * 32 * 64);
#pragma unroll
        for (int i = 0; i < 4; ++i)
            gload_lds16(Bb + (long)i * 32 * 1024 + ko, lb + i * 32 * 64);
        __syncthreads();
#pragma unroll
        for (int kk = 0; kk < 2; ++kk) {
            bf16x8 af[4], bfr[4];
#pragma unroll
            for (int mt = 0; mt < 4; ++mt) {
                int r = wr * 64 + mt * 16 + (lane & 15);
                int sl = ((lane >> 4) + kk * 4) ^ (r & 7);
                af[mt] = *(const bf16x8*)&sA[r * 64 + sl * 8];
            }
#pragma unroll
            for (int nt = 0; nt < 4; ++nt) {
                int r = wc * 64 + nt * 16 + (lane & 15);
                int sl = ((lane >> 4) + kk * 4) ^ (r & 7);
                bfr[nt] = *(const bf16x8*)&sB[r * 64 + sl * 8];
            }
#pragma unroll
            for (int mt = 0; mt < 4; ++mt)
#pragma unroll
                for (int nt = 0; nt < 4; ++nt)
                    acc[mt][nt] = MFMA16(af[mt], bfr[nt], acc[mt][nt]);
        }
        __syncthreads();
    }

    if constexpr (MODE == 2) {
        float* out = (float*)ouse;
#pragma unroll
        for (int nt = 0; nt < 4; ++nt) {
            int col = bn + wc * 64 + nt * 16 + (lane & 15);
            float bs = buse[col];
#pragma unroll
            for (int mt = 0; mt < 4; ++mt) {
                long g0 = bm + wr * 64 + mt * 16 + ((lane >> 4) << 2);
#pragma unroll
                for (int r = 0; r < 4; ++r)
                    out[(g0 + r) * 1024 + col] = acc[mt][nt][r] + bs;
            }
        }
    } else {
        ushort_t* out = (ushort_t*)ouse;
        if (!isv) {
            // head-major out [b][h][l][64]; per-mt LDS-transpose. sE aliases
            // sA (dead after the K-loop's final barrier; per-wave segment).
            ushort_t* se = &sA[wv * 1024];
            int hh = (bn + wc * 64) >> 6;
            float bsv[4];
#pragma unroll
            for (int nt = 0; nt < 4; ++nt)
                bsv[nt] = buse[bn + wc * 64 + nt * 16 + (lane & 15)];
#pragma unroll
            for (int mt = 0; mt < 4; ++mt) {
#pragma unroll
                for (int nt = 0; nt < 4; ++nt) {
                    int col = bn + wc * 64 + nt * 16 + (lane & 15);
                    int c = (col & 63) >> 1;             // rope pair index 0..31
                    int outd = ((col & 1) ? 32 : 0) + c;
                    int chunk = outd >> 3, dlo = outd & 7;
#pragma unroll
                    for (int r = 0; r < 4; ++r) {
                        float y = acc[mt][nt][r] + bsv[nt];
                        float yp = __shfl_xor(y, 1);  // partner column (n^1)
                        int row = ((lane >> 4) << 2) + r;  // 0..15 in mt-tile
                        int l = ((int)bm + wr * 64 + mt * 16 + row) & 8191;
                        float2 sc = rope[l * 32 + c];
                        float val = ((col & 1) ? (y * sc.x - yp * sc.y)
                                               : (y * sc.x + yp * sc.y)) * oscale;
                        se[row * 64 + ((chunk ^ (row & 7)) << 3) + dlo] = f2bf(val);
                    }
                }
                asm volatile("s_waitcnt lgkmcnt(0)" ::: "memory");
#pragma unroll
                for (int i = 0; i < 2; ++i) {
                    int row = i * 8 + (lane >> 3);       // 0..15
                    int cb = lane & 7;
                    ushort8 vv = *(const ushort8*)&se[row * 64 + ((cb ^ (row & 7)) << 3)];
                    int m = (int)bm + wr * 64 + mt * 16 + row;
                    int bb = m >> 13, l = m & 8191;
                    *(ushort8*)&out[(((long)(bb * 16 + hh)) * 8192 + l) * 64 + cb * 8] = vv;
                }
                // DS ops are per-wave in-order: next mt's writes can't pass reads.
            }
        } else {
            // vT[b][h][d][w'] <- y[m=b*512+w][n=h*64+d], w' key-permuted
#pragma unroll
            for (int nt = 0; nt < 4; ++nt) {
                int col = bn + wc * 64 + nt * 16 + (lane & 15);
                float bs = buse[col];
                int hh = col >> 6, d = col & 63;
#pragma unroll
                for (int mt = 0; mt < 4; ++mt) {
                    int m0 = (int)bm + wr * 64 + mt * 16 + ((lane >> 4) << 2);
#pragma unroll
                    for (int r = 0; r < 4; ++r) {
                        int m = m0 + r;
                        int bb = m >> 9, w = m & 511;
                        // key-permutation so PV A-frag is register-local:
                        int t = w & 31;
                        int s = (t < 16) ? ((t >> 2) * 8 + (t & 3))
                                         : (((t & 15) >> 2) * 8 + 4 + (t & 3));
                        int wp = (w & ~31) | s;
                        out[(((long)(bb * 16 + hh)) * 64 + d) * 512 + wp] =
                            f2bf(acc[mt][nt][r] + bs);
                    }
                }
            }
        }
    }
}

// ---------------------------------------------------------------------------
// Attention (R14 — accepted at ~107us, 176 VGPR, no spill; latency-bound at
// 2 blocks/CU, LDS-capped by the irreducible 64KB K-window).
// ---------------------------------------------------------------------------
__global__ __launch_bounds__(256) void attn(const ushort_t* __restrict__ qr,
                                            const ushort_t* __restrict__ kr,
                                            const ushort_t* __restrict__ vT,
                                            ushort_t* __restrict__ ctx) {
    __shared__ __align__(16) ushort_t sK[512 * 64];   // 64 KB ring
    __shared__ __align__(16) ushort_t sE[4][1024];    // ctx transpose, 8 KB
    const int bid = blockIdx.x;
    const int gc = bid & 15, h = (bid >> 4) & 15, b = bid >> 8;
    const int tid = threadIdx.x, lane = tid & 63, wv = tid >> 6;

    const f32x4 kZero = {0.f, 0.f, 0.f, 0.f};
    const u32x4 kOneU = {0x3F803F80u, 0x3F803F80u, 0x3F803F80u, 0x3F803F80u};
    const bf16x8 vone = __builtin_bit_cast(bf16x8, kOneU);  // bf16 1.0 x8

    const ushort_t* khead = kr + ((long)(b * 16 + h)) * 8192 * 64;
    const ushort_t* qhead = qr + ((long)(b * 16 + h)) * 8192 * 64;
    const ushort_t* vb = vT + ((long)(b * 16 + h)) * 64 * 512;

    // prologue: stage rows [gc*512, gc*512+512) -> slot = row & 511
    {
        const long base = (long)gc * 512;
#pragma unroll
        for (int i = 0; i < 16; ++i) {
            int idx = i * 256 + tid;
            int row = idx >> 3, sl = idx & 7;
            int chunk = sl ^ (row & 7);
            gload_lds16(khead + (base + row) * 64 + chunk * 8,
                        (char*)sK + idx * 16);
        }
    }
    __syncthreads();

    ushort_t* se = &sE[wv][0];

#pragma unroll 1
    for (int gi = 0; gi < 8; ++gi) {
        const int g = gc * 8 + gi;
        const int start = g * 64;
        const int climit = 8192 - start;
        const int kclim = climit >> 5;   // #valid kc chunks (>=2)

        // Q fragments (B-operand: lane holds Q[q=lane&15][d=(lane>>4)*8+j])
        const int qrow = start + wv * 16 + (lane & 15);
        const ushort_t* qp = qhead + (long)qrow * 64 + ((lane >> 4) * 8);
        bf16x8 aq0 = *(const bf16x8*)qp;
        bf16x8 aq1 = *(const bf16x8*)(qp + 32);

        f32x4 o[4];
#pragma unroll
        for (int d0 = 0; d0 < 4; ++d0) o[d0] = kZero;
        float ssum = 0.f;

        // V prefetch for kc = 0
        bf16x8 vf0 = *(const bf16x8*)&vb[(long)(0 * 16 + (lane & 15)) * 512 + (lane >> 4) * 8];
        bf16x8 vf1 = *(const bf16x8*)&vb[(long)(1 * 16 + (lane & 15)) * 512 + (lane >> 4) * 8];
        bf16x8 vf2 = *(const bf16x8*)&vb[(long)(2 * 16 + (lane & 15)) * 512 + (lane >> 4) * 8];
        bf16x8 vf3 = *(const bf16x8*)&vb[(long)(3 * 16 + (lane & 15)) * 512 + (lane >> 4) * 8];

#pragma unroll
        for (int kc = 0; kc < 16; ++kc) {
            if (kc == 2) {
                // rows start..start+63 fully consumed by all waves (kc 0,1)
                __syncthreads();
                if (gi < 7) {  // stage next group's 64 new rows into freed slots
#pragma unroll
                    for (int i = 0; i < 2; ++i) {
                        int idx = i * 256 + tid;
                        int rrel = idx >> 3, sl = idx & 7;
                        long rg = (long)start + 512 + rrel;
                        int chunk = sl ^ ((int)rg & 7);
                        long rc = rg > 8191 ? 8191 : rg;
                        gload_lds16(khead + rc * 64 + chunk * 8,
                                    (char*)sK + (start & 511) * 128 + idx * 16);
                    }
                }
            }
            // issue NEXT kc's V loads early (hide L2 latency under QK+exp)
            bf16x8 vn0, vn1, vn2, vn3;
            if (kc < 15) {
                vn0 = *(const bf16x8*)&vb[(long)(0 * 16 + (lane & 15)) * 512 + (kc + 1) * 32 + (lane >> 4) * 8];
                vn1 = *(const bf16x8*)&vb[(long)(1 * 16 + (lane & 15)) * 512 + (kc + 1) * 32 + (lane >> 4) * 8];
                vn2 = *(const bf16x8*)&vb[(long)(2 * 16 + (lane & 15)) * 512 + (kc + 1) * 32 + (lane >> 4) * 8];
                vn3 = *(const bf16x8*)&vb[(long)(3 * 16 + (lane & 15)) * 512 + (kc + 1) * 32 + (lane >> 4) * 8];
            }
            bf16x8 pa;
            if (kc < kclim) {   // wave-uniform: all 32 keys of this kc valid
                // K fragments (A-operand: lane holds K[key=tile*16+(lane&15)][d])
                int c0 = kc * 32 + (lane & 15);
                int c1 = c0 + 16;
                int slot0 = (start + c0) & 511, x0 = slot0 & 7;
                int slot1 = (start + c1) & 511, x1 = slot1 & 7;
                bf16x8 kb00 = *(const bf16x8*)&sK[slot0 * 64 + (((lane >> 4)) ^ x0) * 8];
                bf16x8 kb01 = *(const bf16x8*)&sK[slot0 * 64 + ((4 + (lane >> 4)) ^ x0) * 8];
                bf16x8 kb10 = *(const bf16x8*)&sK[slot1 * 64 + (((lane >> 4)) ^ x1) * 8];
                bf16x8 kb11 = *(const bf16x8*)&sK[slot1 * 64 + ((4 + (lane >> 4)) ^ x1) * 8];
                __builtin_amdgcn_s_setprio(1);
                f32x4 s0 = MFMA16(kb00, aq0, kZero);
                s0 = MFMA16(kb01, aq1, s0);
                f32x4 s1 = MFMA16(kb10, aq0, kZero);
                s1 = MFMA16(kb11, aq1, s1);
                __builtin_amdgcn_s_setprio(0);

                float p0[4], p1[4];
#pragma unroll
                for (int r = 0; r < 4; ++r) {
                    p0[r] = __expf(s0[r] * 0.125f);
                    p1[r] = __expf(s1[r] * 0.125f);
                    ssum += p0[r] + p1[r];
                }
                pa[0] = (__bf16)p0[0]; pa[1] = (__bf16)p0[1];
                pa[2] = (__bf16)p0[2]; pa[3] = (__bf16)p0[3];
                pa[4] = (__bf16)p1[0]; pa[5] = (__bf16)p1[1];
                pa[6] = (__bf16)p1[2]; pa[7] = (__bf16)p1[3];
            } else {            // fully-masked chunk: p = exp(0) = 1 for all
                pa = vone;
                ssum += 8.0f;
            }
            o[0] = MFMA16(pa, vf0, o[0]);
            o[1] = MFMA16(pa, vf1, o[1]);
            o[2] = MFMA16(pa, vf2, o[2]);
            o[3] = MFMA16(pa, vf3, o[3]);
            if (kc < 15) { vf0 = vn0; vf1 = vn1; vf2 = vn2; vf3 = vn3; }
        }

        // total sum per q = lane&15 (4 lane-groups hold disjoint key subsets)
        ssum += __shfl_xor(ssum, 16);
        ssum += __shfl_xor(ssum, 32);
        float rin = 1.0f / ssum;
        float si[4];
#pragma unroll
        for (int r = 0; r < 4; ++r)
            si[r] = __shfl(rin, ((lane >> 4) << 2) + r);  // rin for q-row of o

        // ctx write via LDS transpose -> full-line ushort8 stores
#pragma unroll
        for (int d0 = 0; d0 < 4; ++d0) {
#pragma unroll
            for (int r = 0; r < 4; ++r) {
                int row = ((lane >> 4) << 2) + r;        // 0..15 (q within tile)
                int d = d0 * 16 + (lane & 15);           // 0..63
                se[row * 64 + (((d >> 3) ^ (row & 7)) << 3) + (d & 7)] =
                    f2bfc(o[d0][r] * si[r]);
            }
        }
        asm volatile("s_waitcnt lgkmcnt(0)" ::: "memory");
#pragma unroll
        for (int i = 0; i < 2; ++i) {
            int row = i * 8 + (lane >> 3);
            int cb = lane & 7;
            ushort8 vv = *(const ushort8*)&se[row * 64 + ((cb ^ (row & 7)) << 3)];
            int l = start + wv * 16 + row;
            *(ushort8*)&ctx[((long)(b * 8192 + l)) * 1024 + h * 64 + cb * 8] = vv;
        }
    }
}

// ---------------------------------------------------------------------------
extern "C" void kernel_launch(void* const* d_in, const int* in_sizes, int n_in,
                              void* d_out, int out_size, void* d_ws, size_t ws_size,
                              hipStream_t stream) {
    const float* query = (const float*)d_in[0];
    const float* key_ = (const float*)d_in[1];
    const float* value = (const float*)d_in[2];
    const float* Wq = (const float*)d_in[3];
    const float* bq = (const float*)d_in[4];
    const float* Wk = (const float*)d_in[5];
    const float* bk = (const float*)d_in[6];
    const float* Wv = (const float*)d_in[7];
    const float* bv = (const float*)d_in[8];
    const float* Wo = (const float*)d_in[9];
    const float* bo = (const float*)d_in[10];
    float* out = (float*)d_out;
    char* ws = (char*)d_ws;

    // workspace layout; Xbf: query-bf16 -> (after attn) ctx
    // key-bf16 lives in d_out (scratch; consumed by GEMM-K, overwritten by
    // the final MODE-2 GEMM which fully rewrites d_out).
    ushort_t* Xbf = (ushort_t*)(ws);
    ushort_t* Wqb = (ushort_t*)(ws + 33554432L);
    ushort_t* Wkb = (ushort_t*)(ws + 33554432L + 2097152L);
    ushort_t* Wvb = (ushort_t*)(ws + 33554432L + 2 * 2097152L);
    ushort_t* Wob = (ushort_t*)(ws + 33554432L + 3 * 2097152L);
    float2* rope = (float2*)(ws + 41943040L);
    ushort_t* qrb = (ushort_t*)(ws + 44040192L);
    ushort_t* krb = (ushort_t*)(ws + 77594624L);
    ushort_t* vin = (ushort_t*)(ws + 111149056L);
    ushort_t* vTb = (ushort_t*)(ws + 113246208L);
    ushort_t* keybf = (ushort_t*)d_out;

    prep_all<<<19968, 256, 0, stream>>>(query, key_, Wq, Wk, Wv, Wo,
                                        Wqb, Wkb, Wvb, Wob,
                                        value, vin, rope, Xbf, keybf);

    // merged Q+K+V projection (2112 blocks; Q half, K half, V tail)
    gemm_bt<1><<<dim3(264, 8), 256, 0, stream>>>(Xbf, Wqb, bq, qrb, rope, 1.0f,
                                                 keybf, Wkb, bk, krb,
                                                 vin, Wvb, bv, vTb);

    attn<<<512, 256, 0, stream>>>(qrb, krb, vTb, Xbf);
    gemm_bt<2><<<dim3(128, 8), 256, 0, stream>>>(Xbf, Wob, bo, out, nullptr, 1.0f,
                                                 nullptr, nullptr, nullptr, nullptr,
                                                 nullptr, nullptr, nullptr, nullptr);
}

// Round 19
// 302.782 us; speedup vs baseline: 1.2938x; 1.2938x over previous
//
#include <hip/hip_runtime.h>

// ---------------------------------------------------------------------------
// SlidingWindowGroupedAttention  (B=2, L=8192, E=1024, H=16, D=64, W=512, G=64)
// prep_all(ONE launch) -> merged Q+K GEMM+RoPE (head-major; key-bf16 in d_out)
// -> GEMM->vT (V, key-permuted) -> grouped attention (R14, ~107us accepted)
// -> GEMM (+bias, fp32). GEMM K-loop: BK=64, 128B LDS rows, XOR-8 swizzle.
// [R18's V-tail fold into MODE-1 regressed 2x (pointer non-uniformity broke
//  SGPR addressing: VGPR 104->136, FETCH 90->173MB) -- reverted to R17.]
// ---------------------------------------------------------------------------

typedef unsigned short ushort_t;
typedef __attribute__((ext_vector_type(8))) __bf16 bf16x8;
typedef __attribute__((ext_vector_type(4))) float f32x4;
typedef __attribute__((ext_vector_type(8))) unsigned short ushort8;
typedef __attribute__((ext_vector_type(4))) unsigned int u32x4;

#define MFMA16(a, b, c) __builtin_amdgcn_mfma_f32_16x16x32_bf16((a), (b), (c), 0, 0, 0)

static __device__ __forceinline__ ushort_t f2bf(float f) {
    unsigned u = __float_as_uint(f);
    u += 0x7fffu + ((u >> 16) & 1u);   // round-to-nearest-even
    return (ushort_t)(u >> 16);
}

// compiler-fusable bf16 convert (pairs become v_cvt_pk_bf16_f32; RTNE)
static __device__ __forceinline__ ushort_t f2bfc(float f) {
    __bf16 h = (__bf16)f;
    return __builtin_bit_cast(ushort_t, h);
}

typedef __attribute__((address_space(3))) unsigned int lds_u32;
typedef const __attribute__((address_space(1))) unsigned int glb_u32;

static __device__ __forceinline__ void gload_lds16(const void* g, void* l) {
    __builtin_amdgcn_global_load_lds((glb_u32*)g, (lds_u32*)l, 16, 0, 0);
}

static __device__ __forceinline__ void cvt8(const float* __restrict__ in,
                                            ushort_t* __restrict__ out, long i) {
    const float4* p = (const float4*)in + i * 2;
    float4 a = p[0], b = p[1];
    ushort8 o;
    o[0] = f2bf(a.x); o[1] = f2bf(a.y); o[2] = f2bf(a.z); o[3] = f2bf(a.w);
    o[4] = f2bf(b.x); o[5] = f2bf(b.y); o[6] = f2bf(b.z); o[7] = f2bf(b.w);
    *(ushort8*)(out + i * 8) = o;
}

// ---------------------------------------------------------------------------
// prep_all: ONE launch for all elementwise work (19968 blocks):
//   [0,8192)      query fp32->bf16            -> Xbf
//   [8192,16384)  key   fp32->bf16            -> keybf (= d_out scratch)
//   [16384,17408) rope sin/cos table
//   [17408,19456) weight cvt x4
//   [19456,19968) value rows l<512 compact+cvt -> vin
// ---------------------------------------------------------------------------
__global__ __launch_bounds__(256) void prep_all(const float* __restrict__ query,
                                                const float* __restrict__ key_,
                                                const float* __restrict__ w0,
                                                const float* __restrict__ w1,
                                                const float* __restrict__ w2,
                                                const float* __restrict__ w3,
                                                ushort_t* __restrict__ o0,
                                                ushort_t* __restrict__ o1,
                                                ushort_t* __restrict__ o2,
                                                ushort_t* __restrict__ o3,
                                                const float* __restrict__ value,
                                                ushort_t* __restrict__ vin,
                                                float2* __restrict__ rope,
                                                ushort_t* __restrict__ Xbf,
                                                ushort_t* __restrict__ keybf) {
    const int bid = blockIdx.x;
    if (bid < 8192) {
        cvt8(query, Xbf, (long)bid * 256 + threadIdx.x);
    } else if (bid < 16384) {
        cvt8(key_, keybf, (long)(bid - 8192) * 256 + threadIdx.x);
    } else if (bid < 17408) {
        int i = (bid - 16384) * 256 + threadIdx.x;  // 8192*32
        int l = i >> 5, j = i & 31;
        float inv = exp2f(-(float)j * 0.4152410118609203f);  // log2(10000)/32
        float a = (float)l * inv;
        rope[i] = make_float2(sinf(a), cosf(a));
    } else if (bid < 19456) {
        int b2 = bid - 17408;
        int wsel = b2 >> 9;
        const float* in = (wsel == 0) ? w0 : (wsel == 1) ? w1 : (wsel == 2) ? w2 : w3;
        ushort_t* out = (wsel == 0) ? o0 : (wsel == 1) ? o1 : (wsel == 2) ? o2 : o3;
        cvt8(in, out, (long)(b2 & 511) * 256 + threadIdx.x);
    } else {
        int i = (bid - 19456) * 256 + threadIdx.x;  // value rows l<512 compact
        int f = i * 8;
        int m = f >> 10, c = f & 1023;
        long src = ((long)(m >> 9) * 8192 + (m & 511)) * 1024 + c;
        const float4* p = (const float4*)(value + src);
        float4 a = p[0], b = p[1];
        ushort8 o;
        o[0] = f2bf(a.x); o[1] = f2bf(a.y); o[2] = f2bf(a.z); o[3] = f2bf(a.w);
        o[4] = f2bf(b.x); o[5] = f2bf(b.y); o[6] = f2bf(b.z); o[7] = f2bf(b.w);
        *(ushort8*)(vin + f) = o;
    }
}

// ---------------------------------------------------------------------------
// bf16 GEMM  C[M,1024] = A[M,1024] @ W[1024,1024]^T (+bias)
// 128x128 tile, BK=64, 4 waves (2x2), global_load_lds w16.
// LDS rows are 128B (full bank span); slot s of row r holds global chunk
// s ^ (r&7) -> ds_read_b128 spreads every quarter-wave across all 32 banks.
// MODE 1: MERGED Q+K projection (grid 256x8; id>>10 selects inputs); RoPE
//         epilogue, bf16 HEAD-MAJOR out, per-mt sE flush (sE aliases sA).
// MODE 2: fp32 out, XCD swizzle.  MODE 3: vT out, KEY-PERMUTED w.
// ---------------------------------------------------------------------------
template <int MODE>
__global__ __launch_bounds__(256) void gemm_bt(const ushort_t* __restrict__ A,
                                               const ushort_t* __restrict__ Bw,
                                               const float* __restrict__ bias,
                                               void* __restrict__ outp,
                                               const float2* __restrict__ rope,
                                               float oscale,
                                               const ushort_t* __restrict__ A2,
                                               const ushort_t* __restrict__ Bw2,
                                               const float* __restrict__ bias2,
                                               void* __restrict__ outp2) {
    __shared__ __align__(16) ushort_t sA[128 * 64];   // 16KB, 128B rows
    __shared__ __align__(16) ushort_t sB[128 * 64];   // 16KB
    const int tid = threadIdx.x, lane = tid & 63, wv = tid >> 6;
    const int wr = wv >> 1, wc = wv & 1;

    int bmx, bny;
    const ushort_t* Ause = A;
    const ushort_t* Wuse = Bw;
    const float* buse = bias;
    void* ouse = outp;
    if constexpr (MODE == 1) {
        int id = blockIdx.x + 256 * (int)blockIdx.y;   // 0..2047
        int half = id >> 10, q = id & 1023;
        bmx = (q & 7) * 16 + ((q >> 3) & 15);
        bny = q >> 7;
        if (half) { Ause = A2; Wuse = Bw2; buse = bias2; ouse = outp2; }
    } else if constexpr (MODE == 2) {
        int id = blockIdx.x + 128 * (int)blockIdx.y;   // 0..1023
        bmx = (id & 7) * 16 + ((id >> 3) & 15);
        bny = id >> 7;
    } else {
        bmx = blockIdx.x;
        bny = blockIdx.y;
    }
    const long bm = (long)bmx * 128;
    const int bn = bny * 128;

    f32x4 acc[4][4] = {};

    // staging: per instruction 256 thr x 16B = 32 rows x 128B; 4 instr per
    // matrix per kt. thread -> (row32 = tid>>3, slot = tid&7); source chunk
    // ca = slot ^ (row & 7) (row&7 == row32&7 since i*32 = 0 mod 8).
    const int row32 = tid >> 3;      // 0..31
    const int sl8 = tid & 7;         // 16B slot 0..7
    const int ca = sl8 ^ (row32 & 7);
    const ushort_t* Ab = Ause + (bm + row32) * 1024 + ca * 8;
    const ushort_t* Bb = Wuse + (long)(bn + row32) * 1024 + ca * 8;
    ushort_t* la = &sA[tid * 8];     // row32*64 + sl8*8 == tid*8 (linear)
    ushort_t* lb = &sB[tid * 8];

    for (int kt = 0; kt < 16; ++kt) {
        const int ko = kt * 64;
#pragma unroll
        for (int i = 0; i < 4; ++i)
            gload_lds16(Ab + i * 32 * 1024 + ko, la + i * 32 * 64);
#pragma unroll
        for (int i = 0; i < 4; ++i)
            gload_lds16(Bb + (long)i * 32 * 1024 + ko, lb + i * 32 * 64);
        __syncthreads();
#pragma unroll
        for (int kk = 0; kk < 2; ++kk) {
            bf16x8 af[4], bfr[4];
#pragma unroll
            for (int mt = 0; mt < 4; ++mt) {
                int r = wr * 64 + mt * 16 + (lane & 15);
                int sl = ((lane >> 4) + kk * 4) ^ (r & 7);
                af[mt] = *(const bf16x8*)&sA[r * 64 + sl * 8];
            }
#pragma unroll
            for (int nt = 0; nt < 4; ++nt) {
                int r = wc * 64 + nt * 16 + (lane & 15);
                int sl = ((lane >> 4) + kk * 4) ^ (r & 7);
                bfr[nt] = *(const bf16x8*)&sB[r * 64 + sl * 8];
            }
#pragma unroll
            for (int mt = 0; mt < 4; ++mt)
#pragma unroll
                for (int nt = 0; nt < 4; ++nt)
                    acc[mt][nt] = MFMA16(af[mt], bfr[nt], acc[mt][nt]);
        }
        __syncthreads();
    }

    if constexpr (MODE == 2) {
        float* out = (float*)ouse;
#pragma unroll
        for (int nt = 0; nt < 4; ++nt) {
            int col = bn + wc * 64 + nt * 16 + (lane & 15);
            float bs = buse[col];
#pragma unroll
            for (int mt = 0; mt < 4; ++mt) {
                long g0 = bm + wr * 64 + mt * 16 + ((lane >> 4) << 2);
#pragma unroll
                for (int r = 0; r < 4; ++r)
                    out[(g0 + r) * 1024 + col] = acc[mt][nt][r] + bs;
            }
        }
    } else if constexpr (MODE == 1) {
        // head-major out [b][h][l][64]; per-mt LDS-transpose. sE aliases sA
        // (dead after the K-loop's final barrier; per-wave private segment).
        ushort_t* out = (ushort_t*)ouse;
        ushort_t* se = &sA[wv * 1024];
        int hh = (bn + wc * 64) >> 6;
        float bsv[4];
#pragma unroll
        for (int nt = 0; nt < 4; ++nt)
            bsv[nt] = buse[bn + wc * 64 + nt * 16 + (lane & 15)];
#pragma unroll
        for (int mt = 0; mt < 4; ++mt) {
#pragma unroll
            for (int nt = 0; nt < 4; ++nt) {
                int col = bn + wc * 64 + nt * 16 + (lane & 15);
                int c = (col & 63) >> 1;                 // rope pair index 0..31
                int outd = ((col & 1) ? 32 : 0) + c;
                int chunk = outd >> 3, dlo = outd & 7;
#pragma unroll
                for (int r = 0; r < 4; ++r) {
                    float y = acc[mt][nt][r] + bsv[nt];
                    float yp = __shfl_xor(y, 1);     // partner column (n^1)
                    int row = ((lane >> 4) << 2) + r;    // 0..15 within mt-tile
                    int l = ((int)bm + wr * 64 + mt * 16 + row) & 8191;
                    float2 sc = rope[l * 32 + c];
                    float val = ((col & 1) ? (y * sc.x - yp * sc.y)
                                           : (y * sc.x + yp * sc.y)) * oscale;
                    se[row * 64 + ((chunk ^ (row & 7)) << 3) + dlo] = f2bf(val);
                }
            }
            asm volatile("s_waitcnt lgkmcnt(0)" ::: "memory");
#pragma unroll
            for (int i = 0; i < 2; ++i) {
                int row = i * 8 + (lane >> 3);           // 0..15
                int cb = lane & 7;
                ushort8 vv = *(const ushort8*)&se[row * 64 + ((cb ^ (row & 7)) << 3)];
                int m = (int)bm + wr * 64 + mt * 16 + row;
                int bb = m >> 13, l = m & 8191;
                *(ushort8*)&out[(((long)(bb * 16 + hh)) * 8192 + l) * 64 + cb * 8] = vv;
            }
            // DS ops are per-wave in-order: next mt's writes can't pass reads.
        }
    } else {  // MODE 3: vT[b][h][d][w'] <- y[m=b*512+w][n=h*64+d], w' permuted
        ushort_t* out = (ushort_t*)ouse;
#pragma unroll
        for (int nt = 0; nt < 4; ++nt) {
            int col = bn + wc * 64 + nt * 16 + (lane & 15);
            float bs = buse[col];
            int hh = col >> 6, d = col & 63;
#pragma unroll
            for (int mt = 0; mt < 4; ++mt) {
                int m0 = (int)bm + wr * 64 + mt * 16 + ((lane >> 4) << 2);
#pragma unroll
                for (int r = 0; r < 4; ++r) {
                    int m = m0 + r;
                    int bb = m >> 9, w = m & 511;
                    // key-permutation so PV A-frag is register-local:
                    int t = w & 31;
                    int s = (t < 16) ? ((t >> 2) * 8 + (t & 3))
                                     : (((t & 15) >> 2) * 8 + 4 + (t & 3));
                    int wp = (w & ~31) | s;
                    out[(((long)(bb * 16 + hh)) * 64 + d) * 512 + wp] =
                        f2bf(acc[mt][nt][r] + bs);
                }
            }
        }
    }
}

// ---------------------------------------------------------------------------
// Attention (R14 — accepted at ~107us, 176 VGPR, no spill; latency-bound at
// 2 blocks/CU, LDS-capped by the irreducible 64KB K-window).
// ---------------------------------------------------------------------------
__global__ __launch_bounds__(256) void attn(const ushort_t* __restrict__ qr,
                                            const ushort_t* __restrict__ kr,
                                            const ushort_t* __restrict__ vT,
                                            ushort_t* __restrict__ ctx) {
    __shared__ __align__(16) ushort_t sK[512 * 64];   // 64 KB ring
    __shared__ __align__(16) ushort_t sE[4][1024];    // ctx transpose, 8 KB
    const int bid = blockIdx.x;
    const int gc = bid & 15, h = (bid >> 4) & 15, b = bid >> 8;
    const int tid = threadIdx.x, lane = tid & 63, wv = tid >> 6;

    const f32x4 kZero = {0.f, 0.f, 0.f, 0.f};
    const u32x4 kOneU = {0x3F803F80u, 0x3F803F80u, 0x3F803F80u, 0x3F803F80u};
    const bf16x8 vone = __builtin_bit_cast(bf16x8, kOneU);  // bf16 1.0 x8

    const ushort_t* khead = kr + ((long)(b * 16 + h)) * 8192 * 64;
    const ushort_t* qhead = qr + ((long)(b * 16 + h)) * 8192 * 64;
    const ushort_t* vb = vT + ((long)(b * 16 + h)) * 64 * 512;

    // prologue: stage rows [gc*512, gc*512+512) -> slot = row & 511
    {
        const long base = (long)gc * 512;
#pragma unroll
        for (int i = 0; i < 16; ++i) {
            int idx = i * 256 + tid;
            int row = idx >> 3, sl = idx & 7;
            int chunk = sl ^ (row & 7);
            gload_lds16(khead + (base + row) * 64 + chunk * 8,
                        (char*)sK + idx * 16);
        }
    }
    __syncthreads();

    ushort_t* se = &sE[wv][0];

#pragma unroll 1
    for (int gi = 0; gi < 8; ++gi) {
        const int g = gc * 8 + gi;
        const int start = g * 64;
        const int climit = 8192 - start;
        const int kclim = climit >> 5;   // #valid kc chunks (>=2)

        // Q fragments (B-operand: lane holds Q[q=lane&15][d=(lane>>4)*8+j])
        const int qrow = start + wv * 16 + (lane & 15);
        const ushort_t* qp = qhead + (long)qrow * 64 + ((lane >> 4) * 8);
        bf16x8 aq0 = *(const bf16x8*)qp;
        bf16x8 aq1 = *(const bf16x8*)(qp + 32);

        f32x4 o[4];
#pragma unroll
        for (int d0 = 0; d0 < 4; ++d0) o[d0] = kZero;
        float ssum = 0.f;

        // V prefetch for kc = 0
        bf16x8 vf0 = *(const bf16x8*)&vb[(long)(0 * 16 + (lane & 15)) * 512 + (lane >> 4) * 8];
        bf16x8 vf1 = *(const bf16x8*)&vb[(long)(1 * 16 + (lane & 15)) * 512 + (lane >> 4) * 8];
        bf16x8 vf2 = *(const bf16x8*)&vb[(long)(2 * 16 + (lane & 15)) * 512 + (lane >> 4) * 8];
        bf16x8 vf3 = *(const bf16x8*)&vb[(long)(3 * 16 + (lane & 15)) * 512 + (lane >> 4) * 8];

#pragma unroll
        for (int kc = 0; kc < 16; ++kc) {
            if (kc == 2) {
                // rows start..start+63 fully consumed by all waves (kc 0,1)
                __syncthreads();
                if (gi < 7) {  // stage next group's 64 new rows into freed slots
#pragma unroll
                    for (int i = 0; i < 2; ++i) {
                        int idx = i * 256 + tid;
                        int rrel = idx >> 3, sl = idx & 7;
                        long rg = (long)start + 512 + rrel;
                        int chunk = sl ^ ((int)rg & 7);
                        long rc = rg > 8191 ? 8191 : rg;
                        gload_lds16(khead + rc * 64 + chunk * 8,
                                    (char*)sK + (start & 511) * 128 + idx * 16);
                    }
                }
            }
            // issue NEXT kc's V loads early (hide L2 latency under QK+exp)
            bf16x8 vn0, vn1, vn2, vn3;
            if (kc < 15) {
                vn0 = *(const bf16x8*)&vb[(long)(0 * 16 + (lane & 15)) * 512 + (kc + 1) * 32 + (lane >> 4) * 8];
                vn1 = *(const bf16x8*)&vb[(long)(1 * 16 + (lane & 15)) * 512 + (kc + 1) * 32 + (lane >> 4) * 8];
                vn2 = *(const bf16x8*)&vb[(long)(2 * 16 + (lane & 15)) * 512 + (kc + 1) * 32 + (lane >> 4) * 8];
                vn3 = *(const bf16x8*)&vb[(long)(3 * 16 + (lane & 15)) * 512 + (kc + 1) * 32 + (lane >> 4) * 8];
            }
            bf16x8 pa;
            if (kc < kclim) {   // wave-uniform: all 32 keys of this kc valid
                // K fragments (A-operand: lane holds K[key=tile*16+(lane&15)][d])
                int c0 = kc * 32 + (lane & 15);
                int c1 = c0 + 16;
                int slot0 = (start + c0) & 511, x0 = slot0 & 7;
                int slot1 = (start + c1) & 511, x1 = slot1 & 7;
                bf16x8 kb00 = *(const bf16x8*)&sK[slot0 * 64 + (((lane >> 4)) ^ x0) * 8];
                bf16x8 kb01 = *(const bf16x8*)&sK[slot0 * 64 + ((4 + (lane >> 4)) ^ x0) * 8];
                bf16x8 kb10 = *(const bf16x8*)&sK[slot1 * 64 + (((lane >> 4)) ^ x1) * 8];
                bf16x8 kb11 = *(const bf16x8*)&sK[slot1 * 64 + ((4 + (lane >> 4)) ^ x1) * 8];
                __builtin_amdgcn_s_setprio(1);
                f32x4 s0 = MFMA16(kb00, aq0, kZero);
                s0 = MFMA16(kb01, aq1, s0);
                f32x4 s1 = MFMA16(kb10, aq0, kZero);
                s1 = MFMA16(kb11, aq1, s1);
                __builtin_amdgcn_s_setprio(0);

                float p0[4], p1[4];
#pragma unroll
                for (int r = 0; r < 4; ++r) {
                    p0[r] = __expf(s0[r] * 0.125f);
                    p1[r] = __expf(s1[r] * 0.125f);
                    ssum += p0[r] + p1[r];
                }
                pa[0] = (__bf16)p0[0]; pa[1] = (__bf16)p0[1];
                pa[2] = (__bf16)p0[2]; pa[3] = (__bf16)p0[3];
                pa[4] = (__bf16)p1[0]; pa[5] = (__bf16)p1[1];
                pa[6] = (__bf16)p1[2]; pa[7] = (__bf16)p1[3];
            } else {            // fully-masked chunk: p = exp(0) = 1 for all
                pa = vone;
                ssum += 8.0f;
            }
            o[0] = MFMA16(pa, vf0, o[0]);
            o[1] = MFMA16(pa, vf1, o[1]);
            o[2] = MFMA16(pa, vf2, o[2]);
            o[3] = MFMA16(pa, vf3, o[3]);
            if (kc < 15) { vf0 = vn0; vf1 = vn1; vf2 = vn2; vf3 = vn3; }
        }

        // total sum per q = lane&15 (4 lane-groups hold disjoint key subsets)
        ssum += __shfl_xor(ssum, 16);
        ssum += __shfl_xor(ssum, 32);
        float rin = 1.0f / ssum;
        float si[4];
#pragma unroll
        for (int r = 0; r < 4; ++r)
            si[r] = __shfl(rin, ((lane >> 4) << 2) + r);  // rin for q-row of o

        // ctx write via LDS transpose -> full-line ushort8 stores
#pragma unroll
        for (int d0 = 0; d0 < 4; ++d0) {
#pragma unroll
            for (int r = 0; r < 4; ++r) {
                int row = ((lane >> 4) << 2) + r;        // 0..15 (q within tile)
                int d = d0 * 16 + (lane & 15);           // 0..63
                se[row * 64 + (((d >> 3) ^ (row & 7)) << 3) + (d & 7)] =
                    f2bfc(o[d0][r] * si[r]);
            }
        }
        asm volatile("s_waitcnt lgkmcnt(0)" ::: "memory");
#pragma unroll
        for (int i = 0; i < 2; ++i) {
            int row = i * 8 + (lane >> 3);
            int cb = lane & 7;
            ushort8 vv = *(const ushort8*)&se[row * 64 + ((cb ^ (row & 7)) << 3)];
            int l = start + wv * 16 + row;
            *(ushort8*)&ctx[((long)(b * 8192 + l)) * 1024 + h * 64 + cb * 8] = vv;
        }
    }
}

// ---------------------------------------------------------------------------
extern "C" void kernel_launch(void* const* d_in, const int* in_sizes, int n_in,
                              void* d_out, int out_size, void* d_ws, size_t ws_size,
                              hipStream_t stream) {
    const float* query = (const float*)d_in[0];
    const float* key_ = (const float*)d_in[1];
    const float* value = (const float*)d_in[2];
    const float* Wq = (const float*)d_in[3];
    const float* bq = (const float*)d_in[4];
    const float* Wk = (const float*)d_in[5];
    const float* bk = (const float*)d_in[6];
    const float* Wv = (const float*)d_in[7];
    const float* bv = (const float*)d_in[8];
    const float* Wo = (const float*)d_in[9];
    const float* bo = (const float*)d_in[10];
    float* out = (float*)d_out;
    char* ws = (char*)d_ws;

    // workspace layout; Xbf: query-bf16 -> (after attn) ctx
    // key-bf16 lives in d_out (scratch; consumed by GEMM-K, overwritten by
    // the final MODE-2 GEMM which fully rewrites d_out).
    ushort_t* Xbf = (ushort_t*)(ws);
    ushort_t* Wqb = (ushort_t*)(ws + 33554432L);
    ushort_t* Wkb = (ushort_t*)(ws + 33554432L + 2097152L);
    ushort_t* Wvb = (ushort_t*)(ws + 33554432L + 2 * 2097152L);
    ushort_t* Wob = (ushort_t*)(ws + 33554432L + 3 * 2097152L);
    float2* rope = (float2*)(ws + 41943040L);
    ushort_t* qrb = (ushort_t*)(ws + 44040192L);
    ushort_t* krb = (ushort_t*)(ws + 77594624L);
    ushort_t* vin = (ushort_t*)(ws + 111149056L);
    ushort_t* vTb = (ushort_t*)(ws + 113246208L);
    ushort_t* keybf = (ushort_t*)d_out;

    prep_all<<<19968, 256, 0, stream>>>(query, key_, Wq, Wk, Wv, Wo,
                                        Wqb, Wkb, Wvb, Wob,
                                        value, vin, rope, Xbf, keybf);

    // merged Q+K projection (2048 blocks; query half then key half)
    gemm_bt<1><<<dim3(256, 8), 256, 0, stream>>>(Xbf, Wqb, bq, qrb, rope, 1.0f,
                                                 keybf, Wkb, bk, krb);
    gemm_bt<3><<<dim3(8, 8), 256, 0, stream>>>(vin, Wvb, bv, vTb, nullptr, 1.0f,
                                               nullptr, nullptr, nullptr, nullptr);

    attn<<<512, 256, 0, stream>>>(qrb, krb, vTb, Xbf);
    gemm_bt<2><<<dim3(128, 8), 256, 0, stream>>>(Xbf, Wob, bo, out, nullptr, 1.0f,
                                                 nullptr, nullptr, nullptr, nullptr);
}